// Round 1
// baseline (3439.354 us; speedup 1.0000x reference)
//
#include <hip/hip_runtime.h>
#include <hip/hip_fp16.h>

#define B_ 64
#define T_ 512
#define I_ 128
#define H_ 512

typedef _Float16 half2v __attribute__((ext_vector_type(2)));

__device__ __forceinline__ float dot2(unsigned a, unsigned b, float c) {
    return __builtin_amdgcn_fdot2(__builtin_bit_cast(half2v, a),
                                  __builtin_bit_cast(half2v, b), c, false);
}

__device__ __forceinline__ unsigned short f32_to_f16b(float f) {
    _Float16 h = (_Float16)f;
    return __builtin_bit_cast(unsigned short, h);
}

// ---------------------------------------------------------------------------
// Kernel 1: W_hid fp32 [H,H] -> packed f16 pairs for `recurrent`. (unchanged)
// Consumer thread (w=t>>6, l=t&63) covers h-slots i in [0,8): h = l + 64*i,
// k-slice of wave w: pairs kp = 32w + 4g + m (g in [0,8), m = dword in uint4).
//  - VGPR part (slots i<6):  uint4 idx ((w*6+i)*8+g)*64 + l   -> dwords [0, 98304)
//  - LDS part  (slots 6,7):  uint4 idx ((w*2+ii)*8+g)*64 + l  -> dwords [98304, 131072)
// ---------------------------------------------------------------------------
__global__ void wconv(const float* __restrict__ Whid,
                      unsigned* __restrict__ Wz) {
    int p = blockIdx.x * 256 + threadIdx.x;   // dword index, 0..131071
    int m  = p & 3;
    int u4 = p >> 2;
    int l, g, w, i;
    if (u4 < 24576) {                 // VGPR part
        l = u4 & 63; g = (u4 >> 6) & 7;
        int r = u4 >> 9;              // 0..47
        w = r / 6; i = r - 6 * w;
    } else {                          // LDS part
        int q = u4 - 24576;           // 0..8191
        l = q & 63; g = (q >> 6) & 7;
        int r = q >> 9;               // 0..15
        w = r >> 1; i = 6 + (r & 1);
    }
    int h  = l + 64 * i;
    int kp = 32 * w + 4 * g + m;
    float w0 = Whid[h * H_ + 2 * kp];
    float w1 = Whid[h * H_ + 2 * kp + 1];
    half2v hw = { (_Float16)w0, (_Float16)w1 };
    Wz[p] = __builtin_bit_cast(unsigned, hw);
}

// ---------------------------------------------------------------------------
// Kernel 2: v_in[b,t,h] = x[b,t,:] @ W_in[h,:] + b_in[h]
// NEW: f16-pair packed tiles in LDS, fdot2 compute, b128 fragment reads with
// XOR column swizzle (group kb of row r stored at col-group kb ^ (r>>2)):
//  - row stride 64 dwords -> every b128 16B-aligned
//  - a-reads: 4 distinct addrs, banks 4*((kb^ty)&7) -> disjoint groups, free
//  - b-reads: 16 addrs, tx & tx+8 share a group -> 2-way = free (m136)
// vs old fp32 version: VALU halves, LDS insts 1024 b32 -> 128 b128 (8x).
// ---------------------------------------------------------------------------
__global__ __launch_bounds__(256) void vin_gemm(const float* __restrict__ x,
                                                const float* __restrict__ Win,
                                                const float* __restrict__ bin,
                                                float* __restrict__ vin) {
    __shared__ __align__(16) unsigned xs[64 * 64];   // 16 KB
    __shared__ __align__(16) unsigned ws[64 * 64];   // 16 KB
    const int tid = threadIdx.x;
    const int m0 = blockIdx.x * 64;
    const int n0 = blockIdx.y * 64;

    #pragma unroll
    for (int r = 0; r < 8; ++r) {
        int gi = r * 256 + tid;       // 0..2047
        int row = gi >> 5;            // 0..63
        int c4 = gi & 31;             // float4 index in the 128-float row
        float4 vx = ((const float4*)(x + (size_t)(m0 + row) * I_))[c4];
        float4 vw = ((const float4*)(Win + (size_t)(n0 + row) * I_))[c4];
        int sw = (row >> 2) & 15;
        int col = 4 * ((c4 >> 1) ^ sw) + (c4 & 1) * 2;  // swizzled dword col
        half2v x01 = { (_Float16)vx.x, (_Float16)vx.y };
        half2v x23 = { (_Float16)vx.z, (_Float16)vx.w };
        half2v w01 = { (_Float16)vw.x, (_Float16)vw.y };
        half2v w23 = { (_Float16)vw.z, (_Float16)vw.w };
        xs[row * 64 + col]     = __builtin_bit_cast(unsigned, x01);
        xs[row * 64 + col + 1] = __builtin_bit_cast(unsigned, x23);
        ws[row * 64 + col]     = __builtin_bit_cast(unsigned, w01);
        ws[row * 64 + col + 1] = __builtin_bit_cast(unsigned, w23);
    }
    __syncthreads();

    const int ty = tid >> 4, tx = tid & 15;
    float acc[4][4] = {};
    #pragma unroll
    for (int kb = 0; kb < 16; ++kb) {     // logical k-group: k in [8kb, 8kb+8)
        uint4 a4[4], b4[4];
        #pragma unroll
        for (int i = 0; i < 4; ++i)
            a4[i] = *(const uint4*)&xs[(ty * 4 + i) * 64 + 4 * (kb ^ ty)];
        #pragma unroll
        for (int j = 0; j < 4; ++j)
            b4[j] = *(const uint4*)&ws[(tx * 4 + j) * 64 + 4 * (kb ^ tx)];
        #pragma unroll
        for (int i = 0; i < 4; ++i)
            #pragma unroll
            for (int j = 0; j < 4; ++j) {
                acc[i][j] = dot2(a4[i].x, b4[j].x, acc[i][j]);
                acc[i][j] = dot2(a4[i].y, b4[j].y, acc[i][j]);
                acc[i][j] = dot2(a4[i].z, b4[j].z, acc[i][j]);
                acc[i][j] = dot2(a4[i].w, b4[j].w, acc[i][j]);
            }
    }

    float4 bv = ((const float4*)(bin + n0))[tx];
    #pragma unroll
    for (int i = 0; i < 4; ++i) {
        int m = m0 + ty * 4 + i;
        float4 o;
        o.x = acc[i][0] + bv.x; o.y = acc[i][1] + bv.y;
        o.z = acc[i][2] + bv.z; o.w = acc[i][3] + bv.w;
        ((float4*)(vin + (size_t)m * H_ + n0))[tx] = o;
    }
}

// ---------------------------------------------------------------------------
// Kernel 3: recurrence. NEW sync structure:
//  - k-partials accumulated via ds_add_f32 into a rotating 3-buffer LDS
//    accumulator (A = add+read target, C = zeroed for use 2 steps ahead).
//    Hazards: zero(s) < BAR(s+1) < adds(s+2) < BAR(s+2) < read(s+2).  Cell
//    read/zero only by its owner thread t (program-ordered).
//  - ONE barrier per step (was 2), lgkm-only (raw s_barrier) -> the o0/o1
//    global stores are never drained on the critical path (no vmcnt(0)).
//  - fr is single-buffered: wave w consumes exactly the fr range its own
//    lanes produce (k-slice [64w,64w+64) == h of threads 64w..64w+63), so
//    visibility is intra-wave: lgkmcnt(0) after the write suffices.
//  - reduce phase: ONE ds_read_b32 (was 8 b32 reads + 7 adds).
// ---------------------------------------------------------------------------
__global__ __launch_bounds__(512, 2)
__attribute__((amdgpu_waves_per_eu(2, 2)))
void recurrent(
        const uint4* __restrict__ Wz4,
        const float* __restrict__ vin,
        const float* __restrict__ init_state,
        const float* __restrict__ b_hid,
        const float* __restrict__ alpha,
        float* __restrict__ out0,
        float* __restrict__ out1) {
    __shared__ uint4 ldsW[8192];        // 128 KB : W slots 6,7
    __shared__ float accb[3][512];      //   6 KB : rotating k-sum accumulators
    __shared__ uint4 frq[32];           //   1 KB : fr as f16 pairs (single buf)

    const int t = threadIdx.x;
    const int b = blockIdx.x;
    const int w = t >> 6, l = t & 63;

    // ---- W slots 0..5 into VGPRs: 48 coalesced uint4 loads ---------------
    uint4 wv[6][8];
    const uint4* wp = Wz4 + (size_t)(w * 48) * 64 + l;
    #pragma unroll
    for (int i = 0; i < 6; ++i)
        #pragma unroll
        for (int g = 0; g < 8; ++g)
            wv[i][g] = wp[(i * 8 + g) * 64];
    #pragma unroll
    for (int i = 0; i < 6; ++i)
        #pragma unroll
        for (int g = 0; g < 8; ++g)
            asm volatile("" : "+v"(wv[i][g].x), "+v"(wv[i][g].y),
                              "+v"(wv[i][g].z), "+v"(wv[i][g].w));

    // ---- W slots 6,7 into LDS: 16 b128 per thread, linear ----------------
    const uint4* lsrc = Wz4 + 24576;
    #pragma unroll
    for (int kk = 0; kk < 16; ++kk) ldsW[kk * 512 + t] = lsrc[kk * 512 + t];

    // ---- init ------------------------------------------------------------
    unsigned short* fr16 = (unsigned short*)frq;      // [512]
    float v = init_state[b * H_ + t];
    fr16[t] = f32_to_f16b(fmaxf(v, 0.0f));
    accb[0][t] = 0.0f; accb[1][t] = 0.0f; accb[2][t] = 0.0f;
    const float bh = b_hid[t];
    const float al = alpha[t];
    const float om = 1.0f - al;

    const float* vinp = vin + (size_t)b * T_ * H_ + t;
    float* o0 = out0 + (size_t)b * T_ * H_ + t;
    float* o1 = out1 + (size_t)b * T_ * H_ + t;

    const int lw0 = (w * 2) * 8 * 64 + l;     // uint4 base, slot 6
    const uint4* fb = frq + w * 8;            // wave-uniform -> broadcast
    float* accA = &accb[0][0];                // current step: add + read
    float* accB = &accb[1][0];                // next step
    float* accC = &accb[2][0];                // zero target (used at s+2)

    __syncthreads();

    for (int s = 0; s < T_; ++s) {
        float vinv = vinp[(size_t)s * H_];         // early issue, used late

        float a0 = 0.f, a1 = 0.f, a2 = 0.f, a3 = 0.f;
        float a4 = 0.f, a5 = 0.f, a6 = 0.f, a7 = 0.f;

        #pragma unroll
        for (int g = 0; g < 8; ++g) {
            uint4 wl0 = ldsW[lw0 + g * 64];        // lane-consecutive b128
            uint4 wl1 = ldsW[lw0 + 512 + g * 64];
            uint4 f = fb[g];                       // broadcast b128
            a0 = dot2(f.x, wv[0][g].x, a0); a0 = dot2(f.y, wv[0][g].y, a0);
            a0 = dot2(f.z, wv[0][g].z, a0); a0 = dot2(f.w, wv[0][g].w, a0);
            a1 = dot2(f.x, wv[1][g].x, a1); a1 = dot2(f.y, wv[1][g].y, a1);
            a1 = dot2(f.z, wv[1][g].z, a1); a1 = dot2(f.w, wv[1][g].w, a1);
            a2 = dot2(f.x, wv[2][g].x, a2); a2 = dot2(f.y, wv[2][g].y, a2);
            a2 = dot2(f.z, wv[2][g].z, a2); a2 = dot2(f.w, wv[2][g].w, a2);
            a3 = dot2(f.x, wv[3][g].x, a3); a3 = dot2(f.y, wv[3][g].y, a3);
            a3 = dot2(f.z, wv[3][g].z, a3); a3 = dot2(f.w, wv[3][g].w, a3);
            a4 = dot2(f.x, wv[4][g].x, a4); a4 = dot2(f.y, wv[4][g].y, a4);
            a4 = dot2(f.z, wv[4][g].z, a4); a4 = dot2(f.w, wv[4][g].w, a4);
            a5 = dot2(f.x, wv[5][g].x, a5); a5 = dot2(f.y, wv[5][g].y, a5);
            a5 = dot2(f.z, wv[5][g].z, a5); a5 = dot2(f.w, wv[5][g].w, a5);
            a6 = dot2(f.x, wl0.x, a6); a6 = dot2(f.y, wl0.y, a6);
            a6 = dot2(f.z, wl0.z, a6); a6 = dot2(f.w, wl0.w, a6);
            a7 = dot2(f.x, wl1.x, a7); a7 = dot2(f.y, wl1.y, a7);
            a7 = dot2(f.z, wl1.z, a7); a7 = dot2(f.w, wl1.w, a7);
        }

        // k-partial accumulation: 8 x ds_add_f32, lane-distinct h -> 2-way
        // bank aliasing only (free).  8 waves add to each cell over the step.
        atomicAdd(&accA[l      ], a0);
        atomicAdd(&accA[l +  64], a1);
        atomicAdd(&accA[l + 128], a2);
        atomicAdd(&accA[l + 192], a3);
        atomicAdd(&accA[l + 256], a4);
        atomicAdd(&accA[l + 320], a5);
        atomicAdd(&accA[l + 384], a6);
        atomicAdd(&accA[l + 448], a7);

        // lgkm-only barrier: adds visible, NO vmcnt drain of o0/o1 stores
        asm volatile("s_waitcnt lgkmcnt(0)" ::: "memory");
        __builtin_amdgcn_s_barrier();

        float sum = accA[t];                       // single b32 read
        float vhid = sum + bh;
        float vnew = om * v + al * (vhid + vinv);
        float frn = fmaxf(vnew, 0.0f);
        fr16[t] = f32_to_f16b(frn);                // write fr ASAP
        float vr = om * vnew + al * vhid;
        v = vnew;
        float frr = fmaxf(vr, 0.0f);
        accC[t] = 0.0f;                            // clean buffer for s+2
        o0[(size_t)s * H_] = frn;
        o1[(size_t)s * H_] = frr;

        // rotate: A <- B, B <- C, C <- old A (old A zeroed next step)
        float* tmp = accA; accA = accB; accB = accC; accC = tmp;

        // fr16 visibility is intra-wave: wait own ds_write, no barrier
        asm volatile("s_waitcnt lgkmcnt(0)" ::: "memory");
    }
}

// ---------------------------------------------------------------------------
extern "C" void kernel_launch(void* const* d_in, const int* in_sizes, int n_in,
                              void* d_out, int out_size, void* d_ws, size_t ws_size,
                              hipStream_t stream) {
    const float* x          = (const float*)d_in[0];
    const float* init_state = (const float*)d_in[1];
    const float* W_in       = (const float*)d_in[2];
    const float* b_in       = (const float*)d_in[3];
    const float* W_hid      = (const float*)d_in[4];
    const float* b_hid      = (const float*)d_in[5];
    const float* alpha      = (const float*)d_in[6];

    float* out0 = (float*)d_out;
    float* out1 = out0 + (size_t)B_ * T_ * H_;

    char* ws = (char*)d_ws;
    float*    vin = (float*)ws;                    // 67,108,864 B
    unsigned* Wz  = (unsigned*)(ws + 67108864);    //    524,288 B

    hipLaunchKernelGGL(wconv, dim3(512), dim3(256), 0, stream,
                       W_hid, Wz);
    hipLaunchKernelGGL(vin_gemm, dim3(512, 8), dim3(256), 0, stream,
                       x, W_in, b_in, vin);
    hipLaunchKernelGGL(recurrent, dim3(64), dim3(512), 0, stream,
                       (const uint4*)Wz, vin, init_state, b_hid, alpha,
                       out0, out1);
}

// Round 2
// 922.512 us; speedup vs baseline: 3.7282x; 3.7282x over previous
//
#include <hip/hip_runtime.h>
#include <hip/hip_fp16.h>

#define B_ 64
#define T_ 512
#define I_ 128
#define H_ 512

typedef _Float16 half2v __attribute__((ext_vector_type(2)));

__device__ __forceinline__ float dot2(unsigned a, unsigned b, float c) {
    return __builtin_amdgcn_fdot2(__builtin_bit_cast(half2v, a),
                                  __builtin_bit_cast(half2v, b), c, false);
}

__device__ __forceinline__ unsigned short f32_to_f16b(float f) {
    _Float16 h = (_Float16)f;
    return __builtin_bit_cast(unsigned short, h);
}

// ---------------------------------------------------------------------------
// Kernel 1: W_hid fp32 [H,H] -> packed f16 pairs for `recurrent`. (unchanged)
// Consumer thread (w=t>>6, l=t&63) covers h-slots i in [0,8): h = l + 64*i,
// k-slice of wave w: pairs kp = 32w + 4g + m (g in [0,8), m = dword in uint4).
//  - VGPR part (slots i<6):  uint4 idx ((w*6+i)*8+g)*64 + l   -> dwords [0, 98304)
//  - LDS part  (slots 6,7):  uint4 idx ((w*2+ii)*8+g)*64 + l  -> dwords [98304, 131072)
// ---------------------------------------------------------------------------
__global__ void wconv(const float* __restrict__ Whid,
                      unsigned* __restrict__ Wz) {
    int p = blockIdx.x * 256 + threadIdx.x;   // dword index, 0..131071
    int m  = p & 3;
    int u4 = p >> 2;
    int l, g, w, i;
    if (u4 < 24576) {                 // VGPR part
        l = u4 & 63; g = (u4 >> 6) & 7;
        int r = u4 >> 9;              // 0..47
        w = r / 6; i = r - 6 * w;
    } else {                          // LDS part
        int q = u4 - 24576;           // 0..8191
        l = q & 63; g = (q >> 6) & 7;
        int r = q >> 9;               // 0..15
        w = r >> 1; i = 6 + (r & 1);
    }
    int h  = l + 64 * i;
    int kp = 32 * w + 4 * g + m;
    float w0 = Whid[h * H_ + 2 * kp];
    float w1 = Whid[h * H_ + 2 * kp + 1];
    half2v hw = { (_Float16)w0, (_Float16)w1 };
    Wz[p] = __builtin_bit_cast(unsigned, hw);
}

// ---------------------------------------------------------------------------
// Kernel 2: v_in[b,t,h] = x[b,t,:] @ W_in[h,:] + b_in[h]
// f16-pair packed tiles in LDS, fdot2 compute, b128 fragment reads with
// XOR column swizzle (group kb of row r stored at col-group kb ^ (r>>2)).
// (kept from round 1 -- passed, absmax unchanged at f16 rounding level)
// ---------------------------------------------------------------------------
__global__ __launch_bounds__(256) void vin_gemm(const float* __restrict__ x,
                                                const float* __restrict__ Win,
                                                const float* __restrict__ bin,
                                                float* __restrict__ vin) {
    __shared__ __align__(16) unsigned xs[64 * 64];   // 16 KB
    __shared__ __align__(16) unsigned ws[64 * 64];   // 16 KB
    const int tid = threadIdx.x;
    const int m0 = blockIdx.x * 64;
    const int n0 = blockIdx.y * 64;

    #pragma unroll
    for (int r = 0; r < 8; ++r) {
        int gi = r * 256 + tid;       // 0..2047
        int row = gi >> 5;            // 0..63
        int c4 = gi & 31;             // float4 index in the 128-float row
        float4 vx = ((const float4*)(x + (size_t)(m0 + row) * I_))[c4];
        float4 vw = ((const float4*)(Win + (size_t)(n0 + row) * I_))[c4];
        int sw = (row >> 2) & 15;
        int col = 4 * ((c4 >> 1) ^ sw) + (c4 & 1) * 2;  // swizzled dword col
        half2v x01 = { (_Float16)vx.x, (_Float16)vx.y };
        half2v x23 = { (_Float16)vx.z, (_Float16)vx.w };
        half2v w01 = { (_Float16)vw.x, (_Float16)vw.y };
        half2v w23 = { (_Float16)vw.z, (_Float16)vw.w };
        xs[row * 64 + col]     = __builtin_bit_cast(unsigned, x01);
        xs[row * 64 + col + 1] = __builtin_bit_cast(unsigned, x23);
        ws[row * 64 + col]     = __builtin_bit_cast(unsigned, w01);
        ws[row * 64 + col + 1] = __builtin_bit_cast(unsigned, w23);
    }
    __syncthreads();

    const int ty = tid >> 4, tx = tid & 15;
    float acc[4][4] = {};
    #pragma unroll
    for (int kb = 0; kb < 16; ++kb) {     // logical k-group: k in [8kb, 8kb+8)
        uint4 a4[4], b4[4];
        #pragma unroll
        for (int i = 0; i < 4; ++i)
            a4[i] = *(const uint4*)&xs[(ty * 4 + i) * 64 + 4 * (kb ^ ty)];
        #pragma unroll
        for (int j = 0; j < 4; ++j)
            b4[j] = *(const uint4*)&ws[(tx * 4 + j) * 64 + 4 * (kb ^ tx)];
        #pragma unroll
        for (int i = 0; i < 4; ++i)
            #pragma unroll
            for (int j = 0; j < 4; ++j) {
                acc[i][j] = dot2(a4[i].x, b4[j].x, acc[i][j]);
                acc[i][j] = dot2(a4[i].y, b4[j].y, acc[i][j]);
                acc[i][j] = dot2(a4[i].z, b4[j].z, acc[i][j]);
                acc[i][j] = dot2(a4[i].w, b4[j].w, acc[i][j]);
            }
    }

    float4 bv = ((const float4*)(bin + n0))[tx];
    #pragma unroll
    for (int i = 0; i < 4; ++i) {
        int m = m0 + ty * 4 + i;
        float4 o;
        o.x = acc[i][0] + bv.x; o.y = acc[i][1] + bv.y;
        o.z = acc[i][2] + bv.z; o.w = acc[i][3] + bv.w;
        ((float4*)(vin + (size_t)m * H_ + n0))[tx] = o;
    }
}

// ---------------------------------------------------------------------------
// Kernel 3: recurrence, one block per batch, k-split by wave.
// EXACT register structure of the 968us baseline (wv[6][8] resident, pbuf
// single-copy, fr16 double-buffered, two barriers/step).  ONLY change:
// both __syncthreads() replaced by {s_waitcnt lgkmcnt(0); s_barrier} --
// preserves all cross-thread LDS ordering (partial writes < A < partial
// reads + fr16 write < B) but never drains vmcnt, so the o0/o1 global
// stores are no longer on the per-step critical path.
// ---------------------------------------------------------------------------
__global__ __launch_bounds__(512, 2)
__attribute__((amdgpu_waves_per_eu(2, 2)))
void recurrent(
        const uint4* __restrict__ Wz4,
        const float* __restrict__ vin,
        const float* __restrict__ init_state,
        const float* __restrict__ b_hid,
        const float* __restrict__ alpha,
        float* __restrict__ out0,
        float* __restrict__ out1) {
    __shared__ uint4 ldsW[8192];        // 128 KB : W slots 6,7
    __shared__ uint4 frbuf4[2][64];     //   2 KB : fr as f16 pairs, dbuf
    __shared__ float pbuf[8][640];      //  20 KB : partials [w][l*10+i]

    const int t = threadIdx.x;
    const int b = blockIdx.x;
    const int w = t >> 6, l = t & 63;

    // ---- W slots 0..5 into VGPRs: 48 coalesced uint4 loads ---------------
    uint4 wv[6][8];
    const uint4* wp = Wz4 + (size_t)(w * 48) * 64 + l;
    #pragma unroll
    for (int i = 0; i < 6; ++i)
        #pragma unroll
        for (int g = 0; g < 8; ++g)
            wv[i][g] = wp[(i * 8 + g) * 64];
    #pragma unroll
    for (int i = 0; i < 6; ++i)
        #pragma unroll
        for (int g = 0; g < 8; ++g)
            asm volatile("" : "+v"(wv[i][g].x), "+v"(wv[i][g].y),
                              "+v"(wv[i][g].z), "+v"(wv[i][g].w));

    // ---- W slots 6,7 into LDS: 16 b128 per thread, linear ----------------
    const uint4* lsrc = Wz4 + 24576;
    #pragma unroll
    for (int kk = 0; kk < 16; ++kk) ldsW[kk * 512 + t] = lsrc[kk * 512 + t];

    // ---- init ------------------------------------------------------------
    unsigned short* fr16 = (unsigned short*)frbuf4;   // [2][512]
    float v = init_state[b * H_ + t];
    fr16[t] = f32_to_f16b(fmaxf(v, 0.0f));
    const float bh = b_hid[t];
    const float al = alpha[t];
    const float om = 1.0f - al;

    const float* vinp = vin + (size_t)b * T_ * H_ + t;
    float* o0 = out0 + (size_t)b * T_ * H_ + t;
    float* o1 = out1 + (size_t)b * T_ * H_ + t;

    const int lw0 = (w * 2) * 8 * 64 + l;     // uint4 base, slot 6
    float* prow = &pbuf[w][l * 10];           // this thread's 8 partials

    __syncthreads();

    for (int s = 0; s < T_; ++s) {
        const int par = s & 1;
        float vinv = vinp[(size_t)s * H_];        // early issue, used late

        const uint4* fb = &frbuf4[par][w * 8];    // wave-uniform -> broadcast
        float a0 = 0.f, a1 = 0.f, a2 = 0.f, a3 = 0.f;
        float a4 = 0.f, a5 = 0.f, a6 = 0.f, a7 = 0.f;

        #pragma unroll
        for (int g = 0; g < 8; ++g) {
            uint4 wl0 = ldsW[lw0 + g * 64];       // lane-consecutive b128
            uint4 wl1 = ldsW[lw0 + 512 + g * 64];
            uint4 f = fb[g];                      // broadcast b128
            a0 = dot2(f.x, wv[0][g].x, a0); a0 = dot2(f.y, wv[0][g].y, a0);
            a0 = dot2(f.z, wv[0][g].z, a0); a0 = dot2(f.w, wv[0][g].w, a0);
            a1 = dot2(f.x, wv[1][g].x, a1); a1 = dot2(f.y, wv[1][g].y, a1);
            a1 = dot2(f.z, wv[1][g].z, a1); a1 = dot2(f.w, wv[1][g].w, a1);
            a2 = dot2(f.x, wv[2][g].x, a2); a2 = dot2(f.y, wv[2][g].y, a2);
            a2 = dot2(f.z, wv[2][g].z, a2); a2 = dot2(f.w, wv[2][g].w, a2);
            a3 = dot2(f.x, wv[3][g].x, a3); a3 = dot2(f.y, wv[3][g].y, a3);
            a3 = dot2(f.z, wv[3][g].z, a3); a3 = dot2(f.w, wv[3][g].w, a3);
            a4 = dot2(f.x, wv[4][g].x, a4); a4 = dot2(f.y, wv[4][g].y, a4);
            a4 = dot2(f.z, wv[4][g].z, a4); a4 = dot2(f.w, wv[4][g].w, a4);
            a5 = dot2(f.x, wv[5][g].x, a5); a5 = dot2(f.y, wv[5][g].y, a5);
            a5 = dot2(f.z, wv[5][g].z, a5); a5 = dot2(f.w, wv[5][g].w, a5);
            a6 = dot2(f.x, wl0.x, a6); a6 = dot2(f.y, wl0.y, a6);
            a6 = dot2(f.z, wl0.z, a6); a6 = dot2(f.w, wl0.w, a6);
            a7 = dot2(f.x, wl1.x, a7); a7 = dot2(f.y, wl1.y, a7);
            a7 = dot2(f.z, wl1.z, a7); a7 = dot2(f.w, wl1.w, a7);
        }

        // partial writes: 4 x b64, stride-10 rows -> 2 lanes/bank (free)
        float2* pr = (float2*)prow;
        pr[0] = make_float2(a0, a1);
        pr[1] = make_float2(a2, a3);
        pr[2] = make_float2(a4, a5);
        pr[3] = make_float2(a6, a7);

        // A: partials visible.  lgkm-only barrier -- no vmcnt drain.
        asm volatile("s_waitcnt lgkmcnt(0)" ::: "memory");
        __builtin_amdgcn_s_barrier();

        // reduction: thread t reduces h = t (hl = l, hi = w)
        float sum = pbuf[0][l * 10 + w] + pbuf[1][l * 10 + w]
                  + pbuf[2][l * 10 + w] + pbuf[3][l * 10 + w]
                  + pbuf[4][l * 10 + w] + pbuf[5][l * 10 + w]
                  + pbuf[6][l * 10 + w] + pbuf[7][l * 10 + w];

        float vhid = sum + bh;
        float vnew = om * v + al * (vhid + vinv);
        float vr   = om * vnew + al * vhid;
        v = vnew;
        float frn = fmaxf(vnew, 0.0f);
        float frr = fmaxf(vr, 0.0f);

        o0[(size_t)s * H_] = frn;                 // fire-and-forget
        o1[(size_t)s * H_] = frr;
        fr16[(par ^ 1) * 512 + t] = f32_to_f16b(frn);

        // B: fr complete + pbuf reads retired before next-step writes.
        asm volatile("s_waitcnt lgkmcnt(0)" ::: "memory");
        __builtin_amdgcn_s_barrier();
    }
}

// ---------------------------------------------------------------------------
extern "C" void kernel_launch(void* const* d_in, const int* in_sizes, int n_in,
                              void* d_out, int out_size, void* d_ws, size_t ws_size,
                              hipStream_t stream) {
    const float* x          = (const float*)d_in[0];
    const float* init_state = (const float*)d_in[1];
    const float* W_in       = (const float*)d_in[2];
    const float* b_in       = (const float*)d_in[3];
    const float* W_hid      = (const float*)d_in[4];
    const float* b_hid      = (const float*)d_in[5];
    const float* alpha      = (const float*)d_in[6];

    float* out0 = (float*)d_out;
    float* out1 = out0 + (size_t)B_ * T_ * H_;

    char* ws = (char*)d_ws;
    float*    vin = (float*)ws;                    // 67,108,864 B
    unsigned* Wz  = (unsigned*)(ws + 67108864);    //    524,288 B

    hipLaunchKernelGGL(wconv, dim3(512), dim3(256), 0, stream,
                       W_hid, Wz);
    hipLaunchKernelGGL(vin_gemm, dim3(512, 8), dim3(256), 0, stream,
                       x, W_in, b_in, vin);
    hipLaunchKernelGGL(recurrent, dim3(64), dim3(512), 0, stream,
                       (const uint4*)Wz, vin, init_state, b_hid, alpha,
                       out0, out1);
}